// Round 12
// baseline (1112.510 us; speedup 1.0000x reference)
//
#include <hip/hip_runtime.h>
#include <hip/hip_bf16.h>

#define SEQ 2048
#define BATCH 2
#define NH 16
#define DM 1024
#define DEPTH 64
#define MROWS (BATCH * SEQ)   // 4096

typedef __attribute__((ext_vector_type(8))) short bf16x8;
typedef __attribute__((ext_vector_type(4))) float f32x4;

__device__ __forceinline__ float b2f(ushort u) {
    union { uint i; float f; } v; v.i = ((uint)u) << 16; return v.f;
}
__device__ __forceinline__ ushort f2b(float f) {
    __hip_bfloat16 h = __float2bfloat16(f);
    return *reinterpret_cast<ushort*>(&h);
}

__device__ __forceinline__ void gload_lds16(const void* g, void* l) {
    __builtin_amdgcn_global_load_lds((const __attribute__((address_space(1))) void*)g,
                                     (__attribute__((address_space(3))) void*)l, 16, 0, 0);
}

// ---------------- fp32 -> bf16 elementwise ----------------
__global__ __launch_bounds__(256) void convert_f32_bf16(const float* __restrict__ in,
                                                        ushort* __restrict__ outp, int n4) {
    int i = blockIdx.x * 256 + threadIdx.x;
    if (i < n4) {
        const float4 v = ((const float4*)in)[i];
        ushort4 o;
        o.x = f2b(v.x); o.y = f2b(v.y); o.z = f2b(v.z); o.w = f2b(v.w);
        ((ushort4*)outp)[i] = o;
    }
}

// ---------------- 4x fused: fp32 W[K][N] -> bf16 Wt[N][K], z selects weight ----------------
__global__ __launch_bounds__(256) void transpose_convert4(const float* __restrict__ w0,
                                                          const float* __restrict__ w1,
                                                          const float* __restrict__ w2,
                                                          const float* __restrict__ w3,
                                                          ushort* __restrict__ WtBase) {
    __shared__ float tile[32][33];
    const int z = blockIdx.z;
    const float* W = (z == 0) ? w0 : (z == 1) ? w1 : (z == 2) ? w2 : w3;
    ushort* Wt = WtBase + (size_t)z * DM * DM;
    const int bx = blockIdx.x * 32;  // n base
    const int by = blockIdx.y * 32;  // k base
    const int tx = threadIdx.x & 31, ty = threadIdx.x >> 5;
#pragma unroll
    for (int i = 0; i < 32; i += 8)
        tile[ty + i][tx] = W[(size_t)(by + ty + i) * DM + bx + tx];
    __syncthreads();
#pragma unroll
    for (int i = 0; i < 32; i += 8)
        Wt[(size_t)(bx + ty + i) * DM + by + tx] = f2b(tile[tx][ty + i]);
}

// ---------------- fused QKV GEMM: [4096,1024] @ [1024,3072] + bias -> bf16 ----------------
// Q bank (bank==0) is pre-scaled by 1/sqrt(DEPTH)=0.125 so attn skips the logit scale.
__global__ __launch_bounds__(256) void gemm_qkv_mfma(const ushort* __restrict__ A,
                                                     const ushort* __restrict__ WtAll,
                                                     const float* __restrict__ bq,
                                                     const float* __restrict__ bk,
                                                     const float* __restrict__ bv,
                                                     ushort* __restrict__ OutBase) {
    __shared__ __align__(16) ushort As[128 * 32];
    __shared__ __align__(16) ushort Bs[128 * 32];

    const int t    = threadIdx.x;
    const int lane = t & 63;
    const int w    = t >> 6;
    const int wr   = w >> 1, wc = w & 1;
    const int row0 = blockIdx.y * 128;
    const int col0 = blockIdx.x * 128;           // 0..2944
    const int bank = col0 >> 10;                 // 0,1,2
    const float* bias = (bank == 0) ? bq : (bank == 1) ? bk : bv;
    const float scale = (bank == 0) ? 0.125f : 1.0f;
    const int ccol0 = col0 & 1023;
    ushort* Cout = OutBase + (size_t)bank * MROWS * DM;

    f32x4 acc[4][4];
#pragma unroll
    for (int mi = 0; mi < 4; ++mi)
#pragma unroll
        for (int ni = 0; ni < 4; ++ni) acc[mi][ni] = (f32x4){0.f, 0.f, 0.f, 0.f};

    const int sr = t >> 2;
    const int sc = (t & 3) * 8;

    for (int k0 = 0; k0 < DM; k0 += 32) {
        gload_lds16(&A[(size_t)(row0 + sr) * DM + k0 + sc],          &As[w * 512]);
        gload_lds16(&A[(size_t)(row0 + 64 + sr) * DM + k0 + sc],     &As[2048 + w * 512]);
        gload_lds16(&WtAll[(size_t)(col0 + sr) * DM + k0 + sc],      &Bs[w * 512]);
        gload_lds16(&WtAll[(size_t)(col0 + 64 + sr) * DM + k0 + sc], &Bs[2048 + w * 512]);
        __syncthreads();

        bf16x8 af[4], bfr[4];
#pragma unroll
        for (int mi = 0; mi < 4; ++mi)
            af[mi] = *(const bf16x8*)&As[(wr * 64 + mi * 16 + (lane & 15)) * 32 + (lane >> 4) * 8];
#pragma unroll
        for (int ni = 0; ni < 4; ++ni)
            bfr[ni] = *(const bf16x8*)&Bs[(wc * 64 + ni * 16 + (lane & 15)) * 32 + (lane >> 4) * 8];
#pragma unroll
        for (int mi = 0; mi < 4; ++mi)
#pragma unroll
            for (int ni = 0; ni < 4; ++ni)
                acc[mi][ni] = __builtin_amdgcn_mfma_f32_16x16x32_bf16(af[mi], bfr[ni], acc[mi][ni], 0, 0, 0);
        __syncthreads();
    }

    float bb[4];
#pragma unroll
    for (int ni = 0; ni < 4; ++ni) bb[ni] = bias[ccol0 + wc * 64 + ni * 16 + (lane & 15)];

#pragma unroll
    for (int mi = 0; mi < 4; ++mi) {
        const int row = row0 + wr * 64 + mi * 16 + (lane >> 4) * 4;
#pragma unroll
        for (int ni = 0; ni < 4; ++ni) {
            const int col = ccol0 + wc * 64 + ni * 16 + (lane & 15);
#pragma unroll
            for (int r = 0; r < 4; ++r)
                Cout[(size_t)(row + r) * DM + col] = f2b((acc[mi][ni][r] + bb[ni]) * scale);
        }
    }
}

// ---------------- bf16 MFMA GEMM: C = A @ Wt^T + bias, fp32 out ----------------
__global__ __launch_bounds__(256) void gemm_mfma_f32(const ushort* __restrict__ A,
                                                     const ushort* __restrict__ Wt,
                                                     const float* __restrict__ bias,
                                                     float* __restrict__ Cout) {
    __shared__ __align__(16) ushort As[128 * 32];
    __shared__ __align__(16) ushort Bs[128 * 32];

    const int t    = threadIdx.x;
    const int lane = t & 63;
    const int w    = t >> 6;
    const int wr   = w >> 1, wc = w & 1;
    const int row0 = blockIdx.y * 128;
    const int col0 = blockIdx.x * 128;

    f32x4 acc[4][4];
#pragma unroll
    for (int mi = 0; mi < 4; ++mi)
#pragma unroll
        for (int ni = 0; ni < 4; ++ni) acc[mi][ni] = (f32x4){0.f, 0.f, 0.f, 0.f};

    const int sr = t >> 2;
    const int sc = (t & 3) * 8;

    for (int k0 = 0; k0 < DM; k0 += 32) {
        gload_lds16(&A[(size_t)(row0 + sr) * DM + k0 + sc],       &As[w * 512]);
        gload_lds16(&A[(size_t)(row0 + 64 + sr) * DM + k0 + sc],  &As[2048 + w * 512]);
        gload_lds16(&Wt[(size_t)(col0 + sr) * DM + k0 + sc],      &Bs[w * 512]);
        gload_lds16(&Wt[(size_t)(col0 + 64 + sr) * DM + k0 + sc], &Bs[2048 + w * 512]);
        __syncthreads();

        bf16x8 af[4], bfr[4];
#pragma unroll
        for (int mi = 0; mi < 4; ++mi)
            af[mi] = *(const bf16x8*)&As[(wr * 64 + mi * 16 + (lane & 15)) * 32 + (lane >> 4) * 8];
#pragma unroll
        for (int ni = 0; ni < 4; ++ni)
            bfr[ni] = *(const bf16x8*)&Bs[(wc * 64 + ni * 16 + (lane & 15)) * 32 + (lane >> 4) * 8];
#pragma unroll
        for (int mi = 0; mi < 4; ++mi)
#pragma unroll
            for (int ni = 0; ni < 4; ++ni)
                acc[mi][ni] = __builtin_amdgcn_mfma_f32_16x16x32_bf16(af[mi], bfr[ni], acc[mi][ni], 0, 0, 0);
        __syncthreads();
    }

    float bb[4];
#pragma unroll
    for (int ni = 0; ni < 4; ++ni) bb[ni] = bias[col0 + wc * 64 + ni * 16 + (lane & 15)];

#pragma unroll
    for (int mi = 0; mi < 4; ++mi) {
        const int row = row0 + wr * 64 + mi * 16 + (lane >> 4) * 4;
#pragma unroll
        for (int ni = 0; ni < 4; ++ni) {
            const int col = col0 + wc * 64 + ni * 16 + (lane & 15);
#pragma unroll
            for (int r = 0; r < 4; ++r)
                Cout[(size_t)(row + r) * DM + col] = acc[mi][ni][r] + bb[ni];
        }
    }
}

// ---------------- V panel transpose: Vh[B,S,H*64] -> Vt[32][64 d][2048 k] bf16 ----------------
__global__ __launch_bounds__(256) void transpose_v(const ushort* __restrict__ Vh,
                                                   ushort* __restrict__ Vt) {
    __shared__ ushort tile[64][80];
    const int t  = threadIdx.x;
    const int bh = blockIdx.x;
    const int k0 = blockIdx.y * 64;
    const int b  = bh >> 4;
    const int h  = bh & 15;
    const size_t panel = (size_t)b * SEQ * DM + (size_t)h * DEPTH;

    {
        const int k = t >> 2, dc = (t & 3) * 16;
        const ushort* src = Vh + panel + (size_t)(k0 + k) * DM + dc;
        *(bf16x8*)&tile[k][dc]     = *(const bf16x8*)src;
        *(bf16x8*)&tile[k][dc + 8] = *(const bf16x8*)(src + 8);
    }
    __syncthreads();
    {
        const int d = t >> 2, kc = (t & 3) * 16;
        bf16x8 o0, o1;
#pragma unroll
        for (int j = 0; j < 8; ++j) o0[j] = tile[kc + j][d];
#pragma unroll
        for (int j = 0; j < 8; ++j) o1[j] = tile[kc + 8 + j][d];
        ushort* dst = Vt + ((size_t)bh * DEPTH + d) * SEQ + k0 + kc;
        *(bf16x8*)dst       = o0;
        *(bf16x8*)(dst + 8) = o1;
    }
}

// ---------------- fused attention v5 (R11) — templated for phase ablation ----------------
// MODE 0: full (real). MODE 1: no attn store (ctx -> scratch). MODE 2: no PV (attn only).
// Dummies run at 2x grid (blockIdx.y & 31) so they surface above the harness fill kernels
// in the top-5 profile with full counters. Real kernel runs LAST so outputs are correct.
template <int MODE>
__global__ __launch_bounds__(512, 2) void attn_fused_kernel(const ushort* __restrict__ Qh,
                                                            const ushort* __restrict__ Kh,
                                                            const ushort* __restrict__ Vt,
                                                            float* __restrict__ attn_out,
                                                            ushort* __restrict__ Ctx) {
    __shared__ __align__(16) ushort P_lds[16 * 2048];   // 64 KB
    float* red = (float*)P_lds;

    const int t    = threadIdx.x;
    const int lane = t & 63;
    const int w    = t >> 6;          // 0..7
    const int qt   = blockIdx.x;      // fast axis -> panel-major dispatch
    const int bh   = blockIdx.y & 31;
    const int b    = bh >> 4;
    const int h    = bh & 15;
    const int q0   = qt * 16;
    const int q    = lane & 15;
    const int g    = lane >> 4;       // 0..3
    const int swz  = (q & 7) << 4;

    const size_t panel = (size_t)b * SEQ * DM + (size_t)h * DEPTH;

    const ushort* Qrow = Qh + panel + (size_t)(q0 + q) * DM + g * 8;
    const bf16x8 qf0 = *(const bf16x8*)Qrow;
    const bf16x8 qf1 = *(const bf16x8*)(Qrow + 32);

    f32x4 acc[16];
#pragma unroll
    for (int kt = 0; kt < 16; ++kt) acc[kt] = (f32x4){0.f, 0.f, 0.f, 0.f};

    const ushort* Kbase = Kh + panel + (size_t)(w * 256) * DM + g * 8;
#pragma unroll
    for (int kt = 0; kt < 16; ++kt) {
        const ushort* Kr = Kbase + (size_t)(kt * 16 + q) * DM;
        const bf16x8 kf0 = *(const bf16x8*)Kr;
        const bf16x8 kf1 = *(const bf16x8*)(Kr + 32);
        acc[kt] = __builtin_amdgcn_mfma_f32_16x16x32_bf16(kf0, qf0, acc[kt], 0, 0, 0);   // swapped
        acc[kt] = __builtin_amdgcn_mfma_f32_16x16x32_bf16(kf1, qf1, acc[kt], 0, 0, 0);
    }

    // softmax stats
    float mm = acc[0][0];
#pragma unroll
    for (int kt = 0; kt < 16; ++kt) {
#pragma unroll
        for (int r = 0; r < 4; ++r) mm = fmaxf(mm, acc[kt][r]);
    }
    mm = fmaxf(mm, __shfl_xor(mm, 16));
    mm = fmaxf(mm, __shfl_xor(mm, 32));
    if (lane < 16) red[w * 16 + lane] = mm;
    __syncthreads();

    float mx = red[q];
#pragma unroll
    for (int ww = 1; ww < 8; ++ww) mx = fmaxf(mx, red[ww * 16 + q]);

    float ssum = 0.f;
#pragma unroll
    for (int kt = 0; kt < 16; ++kt) {
#pragma unroll
        for (int r = 0; r < 4; ++r) {
            const float p = __expf(acc[kt][r] - mx);
            acc[kt][r] = p;
            ssum += p;
        }
    }
    ssum += __shfl_xor(ssum, 16);
    ssum += __shfl_xor(ssum, 32);
    if (lane < 16) red[128 + w * 16 + lane] = ssum;
    __syncthreads();

    float tot = red[128 + q];
#pragma unroll
    for (int ww = 1; ww < 8; ++ww) tot += red[128 + ww * 16 + q];
    const float rinv = 1.f / tot;
    __syncthreads();   // red overlay dead -> P_lds writable

    // pack strip (bf16, swizzled) — feeds store (MODE!=1) and PV (MODE!=2)
    char* Pb = (char*)P_lds;
#pragma unroll
    for (int kt = 0; kt < 16; ++kt) {
        const float p0 = acc[kt][0] * rinv;
        const float p1 = acc[kt][1] * rinv;
        const float p2 = acc[kt][2] * rinv;
        const float p3 = acc[kt][3] * rinv;
        uint2 uu;
        uu.x = (uint)f2b(p0) | ((uint)f2b(p1) << 16);
        uu.y = (uint)f2b(p2) | ((uint)f2b(p3) << 16);
        *(uint2*)(Pb + q * 4096 + ((w * 512 + kt * 32 + g * 8) ^ swz)) = uu;
    }

    if constexpr (MODE != 1) {
        // store: wave w writes rows 0..15, cols [w*256, +256) — 1KB/inst, NT
        float* attn_base = attn_out + ((size_t)bh * SEQ + q0) * SEQ;
#pragma unroll
        for (int it = 0; it < 16; ++it) {
            const int bofs = (w * 512 + lane * 8) ^ ((it & 7) << 4);
            const ushort4 p4 = *(const ushort4*)(Pb + it * 4096 + bofs);
            f32x4 o;
            o[0] = b2f(p4.x); o[1] = b2f(p4.y); o[2] = b2f(p4.z); o[3] = b2f(p4.w);
            __builtin_nontemporal_store(o, (f32x4*)&attn_base[(size_t)it * SEQ + w * 256 + lane * 4]);
        }
    }

    if constexpr (MODE != 2) {
        // PV over own strip
        f32x4 ctx[4];
#pragma unroll
        for (int ni = 0; ni < 4; ++ni) ctx[ni] = (f32x4){0.f, 0.f, 0.f, 0.f};

        const ushort* Vtp = Vt + (size_t)bh * DEPTH * SEQ;
#pragma unroll
        for (int s8 = 0; s8 < 8; ++s8) {
            const bf16x8 af = *(const bf16x8*)(Pb + q * 4096 + ((w * 512 + s8 * 64 + g * 16) ^ swz));
            const int kofs = w * 256 + s8 * 32 + g * 8;
#pragma unroll
            for (int ni = 0; ni < 4; ++ni) {
                const bf16x8 bfr = *(const bf16x8*)&Vtp[(size_t)(ni * 16 + q) * SEQ + kofs];
                ctx[ni] = __builtin_amdgcn_mfma_f32_16x16x32_bf16(af, bfr, ctx[ni], 0, 0, 0);
            }
        }
        __syncthreads();

        float* part = (float*)P_lds;
#pragma unroll
        for (int ni = 0; ni < 4; ++ni) {
#pragma unroll
            for (int r = 0; r < 4; ++r) {
                part[(w * 16 + g * 4 + r) * 64 + ni * 16 + q] = ctx[ni][r];
            }
        }
        __syncthreads();

#pragma unroll
        for (int idx = t; idx < 1024; idx += 512) {
            const int qq = idx >> 6, d = idx & 63;
            float s2 = 0.f;
#pragma unroll
            for (int ww = 0; ww < 8; ++ww) s2 += part[ww * 1024 + idx];
            Ctx[(size_t)(b * SEQ + q0 + qq) * DM + h * DEPTH + d] = f2b(s2);
        }
    }
}

extern "C" void kernel_launch(void* const* d_in, const int* in_sizes, int n_in,
                              void* d_out, int out_size, void* d_ws, size_t ws_size,
                              hipStream_t stream) {
    const float* x  = (const float*)d_in[0];
    const float* wq = (const float*)d_in[1];
    const float* bq = (const float*)d_in[2];
    const float* wk = (const float*)d_in[3];
    const float* bk = (const float*)d_in[4];
    const float* wv = (const float*)d_in[5];
    const float* bv = (const float*)d_in[6];
    const float* wo = (const float*)d_in[7];
    const float* bo = (const float*)d_in[8];

    float* out  = (float*)d_out;                          // [2,2048,1024]
    float* attn = out + (size_t)MROWS * DM;               // [2,16,2048,2048] fp32

    ushort* ws  = (ushort*)d_ws;
    ushort* xb  = ws;                        // 4096x1024 bf16
    ushort* wqt = xb + (size_t)MROWS * DM;   // [wqt|wkt|wvt|wot] contiguous, each 1024x1024
    ushort* wot = wqt + (size_t)3 * DM * DM;
    ushort* Qh  = wot + (size_t)DM * DM;     // [Qh|Kh|Vh] contiguous, each 4096x1024 bf16
    ushort* Kh  = Qh + (size_t)MROWS * DM;
    ushort* Vh  = Kh + (size_t)MROWS * DM;
    ushort* cxb = Vh + (size_t)MROWS * DM;
    ushort* Vt  = cxb + (size_t)MROWS * DM;  // [32][64][2048] bf16
    ushort* ctxScratch = Vt + (size_t)BATCH * NH * DEPTH * SEQ;  // 8MB ablation sink

    convert_f32_bf16<<<dim3(MROWS * DM / 4 / 256), 256, 0, stream>>>(x, xb, MROWS * DM / 4);
    transpose_convert4<<<dim3(DM / 32, DM / 32, 4), 256, 0, stream>>>(wq, wk, wv, wo, wqt);

    gemm_qkv_mfma<<<dim3(3 * DM / 128, MROWS / 128), 256, 0, stream>>>(xb, wqt, bq, bk, bv, Qh);

    transpose_v<<<dim3(BATCH * NH, SEQ / 64), 256, 0, stream>>>(Vh, Vt);

    // --- ablation dummies at 2x grid (surface in top-5 with counters); real kernel runs last ---
    attn_fused_kernel<1><<<dim3(SEQ / 16, 64), 512, 0, stream>>>(Qh, Kh, Vt, attn, ctxScratch);
    attn_fused_kernel<2><<<dim3(SEQ / 16, 64), 512, 0, stream>>>(Qh, Kh, Vt, attn, ctxScratch);
    attn_fused_kernel<0><<<dim3(SEQ / 16, 32), 512, 0, stream>>>(Qh, Kh, Vt, attn, cxb);

    gemm_mfma_f32<<<dim3(DM / 128, MROWS / 128), 256, 0, stream>>>(cxb, wot, bo, out);
}

// Round 13
// 277.058 us; speedup vs baseline: 4.0154x; 4.0154x over previous
//
#include <hip/hip_runtime.h>
#include <hip/hip_bf16.h>

#define SEQ 2048
#define BATCH 2
#define NH 16
#define DM 1024
#define DEPTH 64
#define MROWS (BATCH * SEQ)   // 4096

typedef __attribute__((ext_vector_type(8))) short bf16x8;
typedef __attribute__((ext_vector_type(4))) float f32x4;

__device__ __forceinline__ float b2f(ushort u) {
    union { uint i; float f; } v; v.i = ((uint)u) << 16; return v.f;
}
__device__ __forceinline__ ushort f2b(float f) {
    __hip_bfloat16 h = __float2bfloat16(f);
    return *reinterpret_cast<ushort*>(&h);
}

__device__ __forceinline__ void gload_lds16(const void* g, void* l) {
    __builtin_amdgcn_global_load_lds((const __attribute__((address_space(1))) void*)g,
                                     (__attribute__((address_space(3))) void*)l, 16, 0, 0);
}

// ---------------- fp32 -> bf16 elementwise ----------------
__global__ __launch_bounds__(256) void convert_f32_bf16(const float* __restrict__ in,
                                                        ushort* __restrict__ outp, int n4) {
    int i = blockIdx.x * 256 + threadIdx.x;
    if (i < n4) {
        const float4 v = ((const float4*)in)[i];
        ushort4 o;
        o.x = f2b(v.x); o.y = f2b(v.y); o.z = f2b(v.z); o.w = f2b(v.w);
        ((ushort4*)outp)[i] = o;
    }
}

// ---------------- 4x fused: fp32 W[K][N] -> bf16 Wt[N][K], z selects weight ----------------
__global__ __launch_bounds__(256) void transpose_convert4(const float* __restrict__ w0,
                                                          const float* __restrict__ w1,
                                                          const float* __restrict__ w2,
                                                          const float* __restrict__ w3,
                                                          ushort* __restrict__ WtBase) {
    __shared__ float tile[32][33];
    const int z = blockIdx.z;
    const float* W = (z == 0) ? w0 : (z == 1) ? w1 : (z == 2) ? w2 : w3;
    ushort* Wt = WtBase + (size_t)z * DM * DM;
    const int bx = blockIdx.x * 32;  // n base
    const int by = blockIdx.y * 32;  // k base
    const int tx = threadIdx.x & 31, ty = threadIdx.x >> 5;
#pragma unroll
    for (int i = 0; i < 32; i += 8)
        tile[ty + i][tx] = W[(size_t)(by + ty + i) * DM + bx + tx];
    __syncthreads();
#pragma unroll
    for (int i = 0; i < 32; i += 8)
        Wt[(size_t)(bx + ty + i) * DM + by + tx] = f2b(tile[tx][ty + i]);
}

// ---------------- fused QKV GEMM: [4096,1024] @ [1024,3072] + bias -> bf16 ----------------
// Q bank (bank==0) is pre-scaled by 1/sqrt(DEPTH)=0.125 so attn skips the logit scale.
__global__ __launch_bounds__(256) void gemm_qkv_mfma(const ushort* __restrict__ A,
                                                     const ushort* __restrict__ WtAll,
                                                     const float* __restrict__ bq,
                                                     const float* __restrict__ bk,
                                                     const float* __restrict__ bv,
                                                     ushort* __restrict__ OutBase) {
    __shared__ __align__(16) ushort As[128 * 32];
    __shared__ __align__(16) ushort Bs[128 * 32];

    const int t    = threadIdx.x;
    const int lane = t & 63;
    const int w    = t >> 6;
    const int wr   = w >> 1, wc = w & 1;
    const int row0 = blockIdx.y * 128;
    const int col0 = blockIdx.x * 128;           // 0..2944
    const int bank = col0 >> 10;                 // 0,1,2
    const float* bias = (bank == 0) ? bq : (bank == 1) ? bk : bv;
    const float scale = (bank == 0) ? 0.125f : 1.0f;
    const int ccol0 = col0 & 1023;
    ushort* Cout = OutBase + (size_t)bank * MROWS * DM;

    f32x4 acc[4][4];
#pragma unroll
    for (int mi = 0; mi < 4; ++mi)
#pragma unroll
        for (int ni = 0; ni < 4; ++ni) acc[mi][ni] = (f32x4){0.f, 0.f, 0.f, 0.f};

    const int sr = t >> 2;
    const int sc = (t & 3) * 8;

    for (int k0 = 0; k0 < DM; k0 += 32) {
        gload_lds16(&A[(size_t)(row0 + sr) * DM + k0 + sc],          &As[w * 512]);
        gload_lds16(&A[(size_t)(row0 + 64 + sr) * DM + k0 + sc],     &As[2048 + w * 512]);
        gload_lds16(&WtAll[(size_t)(col0 + sr) * DM + k0 + sc],      &Bs[w * 512]);
        gload_lds16(&WtAll[(size_t)(col0 + 64 + sr) * DM + k0 + sc], &Bs[2048 + w * 512]);
        __syncthreads();

        bf16x8 af[4], bfr[4];
#pragma unroll
        for (int mi = 0; mi < 4; ++mi)
            af[mi] = *(const bf16x8*)&As[(wr * 64 + mi * 16 + (lane & 15)) * 32 + (lane >> 4) * 8];
#pragma unroll
        for (int ni = 0; ni < 4; ++ni)
            bfr[ni] = *(const bf16x8*)&Bs[(wc * 64 + ni * 16 + (lane & 15)) * 32 + (lane >> 4) * 8];
#pragma unroll
        for (int mi = 0; mi < 4; ++mi)
#pragma unroll
            for (int ni = 0; ni < 4; ++ni)
                acc[mi][ni] = __builtin_amdgcn_mfma_f32_16x16x32_bf16(af[mi], bfr[ni], acc[mi][ni], 0, 0, 0);
        __syncthreads();
    }

    float bb[4];
#pragma unroll
    for (int ni = 0; ni < 4; ++ni) bb[ni] = bias[ccol0 + wc * 64 + ni * 16 + (lane & 15)];

#pragma unroll
    for (int mi = 0; mi < 4; ++mi) {
        const int row = row0 + wr * 64 + mi * 16 + (lane >> 4) * 4;
#pragma unroll
        for (int ni = 0; ni < 4; ++ni) {
            const int col = ccol0 + wc * 64 + ni * 16 + (lane & 15);
#pragma unroll
            for (int r = 0; r < 4; ++r)
                Cout[(size_t)(row + r) * DM + col] = f2b((acc[mi][ni][r] + bb[ni]) * scale);
        }
    }
}

// ---------------- bf16 MFMA GEMM: C = A @ Wt^T + bias, fp32 out ----------------
__global__ __launch_bounds__(256) void gemm_mfma_f32(const ushort* __restrict__ A,
                                                     const ushort* __restrict__ Wt,
                                                     const float* __restrict__ bias,
                                                     float* __restrict__ Cout) {
    __shared__ __align__(16) ushort As[128 * 32];
    __shared__ __align__(16) ushort Bs[128 * 32];

    const int t    = threadIdx.x;
    const int lane = t & 63;
    const int w    = t >> 6;
    const int wr   = w >> 1, wc = w & 1;
    const int row0 = blockIdx.y * 128;
    const int col0 = blockIdx.x * 128;

    f32x4 acc[4][4];
#pragma unroll
    for (int mi = 0; mi < 4; ++mi)
#pragma unroll
        for (int ni = 0; ni < 4; ++ni) acc[mi][ni] = (f32x4){0.f, 0.f, 0.f, 0.f};

    const int sr = t >> 2;
    const int sc = (t & 3) * 8;

    for (int k0 = 0; k0 < DM; k0 += 32) {
        gload_lds16(&A[(size_t)(row0 + sr) * DM + k0 + sc],       &As[w * 512]);
        gload_lds16(&A[(size_t)(row0 + 64 + sr) * DM + k0 + sc],  &As[2048 + w * 512]);
        gload_lds16(&Wt[(size_t)(col0 + sr) * DM + k0 + sc],      &Bs[w * 512]);
        gload_lds16(&Wt[(size_t)(col0 + 64 + sr) * DM + k0 + sc], &Bs[2048 + w * 512]);
        __syncthreads();

        bf16x8 af[4], bfr[4];
#pragma unroll
        for (int mi = 0; mi < 4; ++mi)
            af[mi] = *(const bf16x8*)&As[(wr * 64 + mi * 16 + (lane & 15)) * 32 + (lane >> 4) * 8];
#pragma unroll
        for (int ni = 0; ni < 4; ++ni)
            bfr[ni] = *(const bf16x8*)&Bs[(wc * 64 + ni * 16 + (lane & 15)) * 32 + (lane >> 4) * 8];
#pragma unroll
        for (int mi = 0; mi < 4; ++mi)
#pragma unroll
            for (int ni = 0; ni < 4; ++ni)
                acc[mi][ni] = __builtin_amdgcn_mfma_f32_16x16x32_bf16(af[mi], bfr[ni], acc[mi][ni], 0, 0, 0);
        __syncthreads();
    }

    float bb[4];
#pragma unroll
    for (int ni = 0; ni < 4; ++ni) bb[ni] = bias[col0 + wc * 64 + ni * 16 + (lane & 15)];

#pragma unroll
    for (int mi = 0; mi < 4; ++mi) {
        const int row = row0 + wr * 64 + mi * 16 + (lane >> 4) * 4;
#pragma unroll
        for (int ni = 0; ni < 4; ++ni) {
            const int col = col0 + wc * 64 + ni * 16 + (lane & 15);
#pragma unroll
            for (int r = 0; r < 4; ++r)
                Cout[(size_t)(row + r) * DM + col] = acc[mi][ni][r] + bb[ni];
        }
    }
}

// ---------------- V panel transpose: Vh[B,S,H*64] -> Vt[32][64 d][2048 k] bf16 ----------------
__global__ __launch_bounds__(256) void transpose_v(const ushort* __restrict__ Vh,
                                                   ushort* __restrict__ Vt) {
    __shared__ ushort tile[64][80];
    const int t  = threadIdx.x;
    const int bh = blockIdx.x;
    const int k0 = blockIdx.y * 64;
    const int b  = bh >> 4;
    const int h  = bh & 15;
    const size_t panel = (size_t)b * SEQ * DM + (size_t)h * DEPTH;

    {
        const int k = t >> 2, dc = (t & 3) * 16;
        const ushort* src = Vh + panel + (size_t)(k0 + k) * DM + dc;
        *(bf16x8*)&tile[k][dc]     = *(const bf16x8*)src;
        *(bf16x8*)&tile[k][dc + 8] = *(const bf16x8*)(src + 8);
    }
    __syncthreads();
    {
        const int d = t >> 2, kc = (t & 3) * 16;
        bf16x8 o0, o1;
#pragma unroll
        for (int j = 0; j < 8; ++j) o0[j] = tile[kc + j][d];
#pragma unroll
        for (int j = 0; j < 8; ++j) o1[j] = tile[kc + 8 + j][d];
        ushort* dst = Vt + ((size_t)bh * DEPTH + d) * SEQ + k0 + kc;
        *(bf16x8*)dst       = o0;
        *(bf16x8*)(dst + 8) = o1;
    }
}

// ---------------- fused attention v6: LDS-staged K (double-buffered) + swapped QK^T ----------
// Block: 512 threads (8 waves), one (b,h) x 16 q-rows. K panel staged through P_lds
// (2 x 32KB buffers) in 8 chunks of 256 keys via coalesced global_load_lds; fragment
// reads come from LDS (kills the 64-cache-line K gather that made R11 latency-bound).
// Key ownership: wave w owns k = c*256 + w*32 + kt2*16 + g*4 + r (c = chunk).
// Swizzles: K rows byte ^= (row&7)<<4 applied on the GLOBAL source (LDS dest linear,
// m173 pattern); P pack rows byte ^= (q&7)<<4 (R11-verified store/PV offsets).
__global__ __launch_bounds__(512, 2) void attn_fused_kernel(const ushort* __restrict__ Qh,
                                                            const ushort* __restrict__ Kh,
                                                            const ushort* __restrict__ Vt,
                                                            float* __restrict__ attn_out,
                                                            ushort* __restrict__ Ctx) {
    __shared__ __align__(16) ushort P_lds[16 * 2048];   // 64 KB: K staging, then P tile
    __shared__ float red[256];                          // softmax stats (separate 1 KB)

    const int t    = threadIdx.x;
    const int lane = t & 63;
    const int w    = t >> 6;          // 0..7
    const int qt   = blockIdx.x;      // fast axis -> panel-major dispatch
    const int bh   = blockIdx.y;
    const int b    = bh >> 4;
    const int h    = bh & 15;
    const int q0   = qt * 16;
    const int q    = lane & 15;
    const int g    = lane >> 4;       // 0..3
    const int swzP = (q & 7) << 4;
    const int swzK = (q & 7) << 4;

    const size_t panel = (size_t)b * SEQ * DM + (size_t)h * DEPTH;
    char* Pb = (char*)P_lds;

    // Q fragment (B operand), pre-scaled by 0.125 in projection
    const ushort* Qrow = Qh + panel + (size_t)(q0 + q) * DM + g * 8;
    const bf16x8 qf0 = *(const bf16x8*)Qrow;
    const bf16x8 qf1 = *(const bf16x8*)(Qrow + 32);

    f32x4 acc[16];
#pragma unroll
    for (int i = 0; i < 16; ++i) acc[i] = (f32x4){0.f, 0.f, 0.f, 0.f};

    // ---- K staging: chunk c = keys [c*256, c*256+256), 32KB, into buffer c&1.
    // Thread t, inst j: LDS linear byte j*8192 + t*16 -> row j*64 + (t>>3),
    // col (t&7)*16; global source col pre-XOR'd with ((t>>3)&7)<<4 (= row&7 swizzle).
    const char* Ksrc = (const char*)(Kh + panel);
    const int srow  = t >> 3;                 // 0..63 (row within j-group)
    const int scolb = ((t & 7) * 16) ^ ((srow & 7) << 4);
    char* wavedst = Pb + (t >> 6) * 1024;     // wave-uniform

#define STAGE_K(c)                                                                  \
    {                                                                               \
        char* dB = wavedst + ((c) & 1) * 32768;                                     \
        _Pragma("unroll")                                                           \
        for (int j = 0; j < 4; ++j) {                                               \
            const char* gp = Ksrc + (size_t)((c) * 256 + j * 64 + srow) * (DM * 2)  \
                             + scolb;                                               \
            gload_lds16(gp, dB + j * 8192);                                         \
        }                                                                           \
    }

    STAGE_K(0);
    __syncthreads();

#pragma unroll
    for (int c = 0; c < 8; ++c) {
        if (c < 7) STAGE_K(c + 1);            // prefetch next chunk (other buffer)
        const char* kb = Pb + (c & 1) * 32768;
#pragma unroll
        for (int kt2 = 0; kt2 < 2; ++kt2) {
            const char* rowp = kb + (w * 32 + kt2 * 16 + q) * 128;
            const bf16x8 kf0 = *(const bf16x8*)(rowp + ((g * 16) ^ swzK));
            const bf16x8 kf1 = *(const bf16x8*)(rowp + ((64 + g * 16) ^ swzK));
            acc[c * 2 + kt2] = __builtin_amdgcn_mfma_f32_16x16x32_bf16(kf0, qf0, acc[c * 2 + kt2], 0, 0, 0);
            acc[c * 2 + kt2] = __builtin_amdgcn_mfma_f32_16x16x32_bf16(kf1, qf1, acc[c * 2 + kt2], 0, 0, 0);
        }
        __syncthreads();   // drains prefetch + releases buffer c&1 for chunk c+2
    }
#undef STAGE_K

    // ---- softmax stats: lane-local -> lanes {q,q+16,q+32,q+48} -> waves (via red)
    float mm = acc[0][0];
#pragma unroll
    for (int i = 0; i < 16; ++i) {
#pragma unroll
        for (int r = 0; r < 4; ++r) mm = fmaxf(mm, acc[i][r]);
    }
    mm = fmaxf(mm, __shfl_xor(mm, 16));
    mm = fmaxf(mm, __shfl_xor(mm, 32));
    if (lane < 16) red[w * 16 + lane] = mm;
    __syncthreads();

    float mx = red[q];
#pragma unroll
    for (int ww = 1; ww < 8; ++ww) mx = fmaxf(mx, red[ww * 16 + q]);

    float ssum = 0.f;
#pragma unroll
    for (int i = 0; i < 16; ++i) {
#pragma unroll
        for (int r = 0; r < 4; ++r) {
            const float p = __expf(acc[i][r] - mx);
            acc[i][r] = p;
            ssum += p;
        }
    }
    ssum += __shfl_xor(ssum, 16);
    ssum += __shfl_xor(ssum, 32);
    if (lane < 16) red[128 + w * 16 + lane] = ssum;
    __syncthreads();

    float tot = red[128 + q];
#pragma unroll
    for (int ww = 1; ww < 8; ++ww) tot += red[128 + ww * 16 + q];
    const float rinv = 1.f / tot;

    // ---- pack normalized P (bf16, swizzled). K staging data dead; P_lds rows = q.
    // acc[c*2+kt2][r] -> key c*256 + w*32 + kt2*16 + g*4 + r -> byte c*512+w*64+kt2*32+g*8
#pragma unroll
    for (int i = 0; i < 16; ++i) {
        const int c2 = i >> 1, kt2 = i & 1;
        const float p0 = acc[i][0] * rinv;
        const float p1 = acc[i][1] * rinv;
        const float p2 = acc[i][2] * rinv;
        const float p3 = acc[i][3] * rinv;
        uint2 uu;
        uu.x = (uint)f2b(p0) | ((uint)f2b(p1) << 16);
        uu.y = (uint)f2b(p2) | ((uint)f2b(p3) << 16);
        *(uint2*)(Pb + q * 4096 + ((c2 * 512 + w * 64 + kt2 * 32 + g * 8) ^ swzP)) = uu;
    }
    __syncthreads();   // cross-wave interleaved pack -> store needs full tile

    // ---- attn store: wave w writes rows 0..15, cols [w*256,+256); 1KB/inst, NT
    float* attn_base = attn_out + ((size_t)bh * SEQ + q0) * SEQ;
#pragma unroll
    for (int it = 0; it < 16; ++it) {
        const int bofs = (w * 512 + lane * 8) ^ ((it & 7) << 4);
        const ushort4 p4 = *(const ushort4*)(Pb + it * 4096 + bofs);
        f32x4 o;
        o[0] = b2f(p4.x); o[1] = b2f(p4.y); o[2] = b2f(p4.z); o[3] = b2f(p4.w);
        __builtin_nontemporal_store(o, (f32x4*)&attn_base[(size_t)it * SEQ + w * 256 + lane * 4]);
    }

    // ---- PV: wave w over its keys {c*256 + w*32 .. +32}, 8 MFMA steps
    f32x4 ctx[4];
#pragma unroll
    for (int ni = 0; ni < 4; ++ni) ctx[ni] = (f32x4){0.f, 0.f, 0.f, 0.f};

    const ushort* Vtp = Vt + (size_t)bh * DEPTH * SEQ;
#pragma unroll
    for (int c = 0; c < 8; ++c) {
        const bf16x8 af = *(const bf16x8*)(Pb + q * 4096 + ((c * 512 + w * 64 + g * 16) ^ swzP));
        const int kofs = c * 256 + w * 32 + g * 8;
#pragma unroll
        for (int ni = 0; ni < 4; ++ni) {
            const bf16x8 bfr = *(const bf16x8*)&Vtp[(size_t)(ni * 16 + q) * SEQ + kofs];
            ctx[ni] = __builtin_amdgcn_mfma_f32_16x16x32_bf16(af, bfr, ctx[ni], 0, 0, 0);
        }
    }
    __syncthreads();   // all P reads done; reuse P_lds as f32 partials [8][16][64]

    float* part = (float*)P_lds;
#pragma unroll
    for (int ni = 0; ni < 4; ++ni) {
#pragma unroll
        for (int r = 0; r < 4; ++r) {
            part[(w * 16 + g * 4 + r) * 64 + ni * 16 + q] = ctx[ni][r];
        }
    }
    __syncthreads();

#pragma unroll
    for (int idx = t; idx < 1024; idx += 512) {
        const int qq = idx >> 6, d = idx & 63;
        float s2 = 0.f;
#pragma unroll
        for (int ww = 0; ww < 8; ++ww) s2 += part[ww * 1024 + idx];
        Ctx[(size_t)(b * SEQ + q0 + qq) * DM + h * DEPTH + d] = f2b(s2);
    }
}

extern "C" void kernel_launch(void* const* d_in, const int* in_sizes, int n_in,
                              void* d_out, int out_size, void* d_ws, size_t ws_size,
                              hipStream_t stream) {
    const float* x  = (const float*)d_in[0];
    const float* wq = (const float*)d_in[1];
    const float* bq = (const float*)d_in[2];
    const float* wk = (const float*)d_in[3];
    const float* bk = (const float*)d_in[4];
    const float* wv = (const float*)d_in[5];
    const float* bv = (const float*)d_in[6];
    const float* wo = (const float*)d_in[7];
    const float* bo = (const float*)d_in[8];

    float* out  = (float*)d_out;                          // [2,2048,1024]
    float* attn = out + (size_t)MROWS * DM;               // [2,16,2048,2048] fp32

    ushort* ws  = (ushort*)d_ws;
    ushort* xb  = ws;                        // 4096x1024 bf16
    ushort* wqt = xb + (size_t)MROWS * DM;   // [wqt|wkt|wvt|wot] contiguous, each 1024x1024
    ushort* wot = wqt + (size_t)3 * DM * DM;
    ushort* Qh  = wot + (size_t)DM * DM;     // [Qh|Kh|Vh] contiguous, each 4096x1024 bf16
    ushort* Kh  = Qh + (size_t)MROWS * DM;
    ushort* Vh  = Kh + (size_t)MROWS * DM;
    ushort* cxb = Vh + (size_t)MROWS * DM;
    ushort* Vt  = cxb + (size_t)MROWS * DM;  // [32][64][2048] bf16

    convert_f32_bf16<<<dim3(MROWS * DM / 4 / 256), 256, 0, stream>>>(x, xb, MROWS * DM / 4);
    transpose_convert4<<<dim3(DM / 32, DM / 32, 4), 256, 0, stream>>>(wq, wk, wv, wo, wqt);

    gemm_qkv_mfma<<<dim3(3 * DM / 128, MROWS / 128), 256, 0, stream>>>(xb, wqt, bq, bk, bv, Qh);

    transpose_v<<<dim3(BATCH * NH, SEQ / 64), 256, 0, stream>>>(Vh, Vt);

    attn_fused_kernel<<<dim3(SEQ / 16, BATCH * NH), 512, 0, stream>>>(Qh, Kh, Vt, attn, cxb);

    gemm_mfma_f32<<<dim3(DM / 128, MROWS / 128), 256, 0, stream>>>(cxb, wot, bo, out);
}